// Round 2
// baseline (441.159 us; speedup 1.0000x reference)
//
#include <hip/hip_runtime.h>
#include <stdint.h>

#define L_DIM 2048
#define B_DIM 32
#define ENC_DIM 1024
#define M_DIM (L_DIM * B_DIM)

typedef __attribute__((ext_vector_type(4))) float f32x4;
typedef __attribute__((ext_vector_type(8))) short short8;
typedef __attribute__((ext_vector_type(4))) __bf16 bf16x4;

static __device__ __forceinline__ float fast_tanh(float x) {
  float cx = fminf(fmaxf(x, -15.f), 15.f);
  float e = __expf(2.f * cx);
  return (e - 1.f) * __frcp_rn(e + 1.f);
}

static __device__ __forceinline__ void load_lds16(const void* g, void* l) {
  __builtin_amdgcn_global_load_lds((const __attribute__((address_space(1))) void*)g,
                                   (__attribute__((address_space(3))) void*)l, 16, 0, 0);
}

// ---------------- W_enc [K=1024][N=1024] fp32  ->  WT [N][K] bf16 -----------------
__global__ __launch_bounds__(256) void k_wt(const float* __restrict__ W,
                                            unsigned short* __restrict__ WT) {
  __shared__ float tile[64][65];
  const int t = threadIdx.x;
  const int k0 = (blockIdx.x & 15) << 6, n0 = (blockIdx.x >> 4) << 6;
#pragma unroll
  for (int i = 0; i < 16; ++i) {
    int idx = t + (i << 8);
    tile[idx >> 6][idx & 63] = W[(size_t)(k0 + (idx >> 6)) * 1024 + n0 + (idx & 63)];
  }
  __syncthreads();
#pragma unroll
  for (int i = 0; i < 16; ++i) {
    int idx = t + (i << 8);
    int r = idx >> 6, c = idx & 63;
    WT[(size_t)(n0 + r) * 1024 + k0 + c] =
        __builtin_bit_cast(unsigned short, (__bf16)tile[c][r]);
  }
}

// ---------------- q partial: grid 64 = 8 a-blocks x 8 h-blocks, 128 thr -----------
__global__ __launch_bounds__(128) void k_qpart(const float* __restrict__ hidden,
                                               const float* __restrict__ Wh,
                                               float* __restrict__ pq) {
  const int ablk = blockIdx.x & 7, hblk = blockIdx.x >> 3;
  const int a = (ablk << 7) + threadIdx.x;
  float acc[32];
#pragma unroll
  for (int b = 0; b < 32; ++b) acc[b] = 0.f;
  const int h0 = hblk << 7;
  for (int h = h0; h < h0 + 128; ++h) {
    float wv = Wh[(size_t)h * 1024 + a];
#pragma unroll
    for (int b = 0; b < 32; ++b) acc[b] = fmaf(hidden[(b << 10) + h], wv, acc[b]);
  }
#pragma unroll
  for (int b = 0; b < 32; ++b) pq[((size_t)hblk << 15) + (b << 10) + a] = acc[b];
}

__global__ __launch_bounds__(256) void k_qred(const float* __restrict__ pq,
                                              const float* __restrict__ ba,
                                              float* __restrict__ q) {
  int i = blockIdx.x * 256 + threadIdx.x;  // 32768
  float s = ba[i & 1023];
#pragma unroll
  for (int j = 0; j < 8; ++j) s += pq[((size_t)j << 15) + i];
  q[i] = s;
}

// ---------------- fused keys-GEMM + tanh.v reduction ------------------------------
// A = enc viewed [M=65536][K=1024] fp32 (row = l*32+b), B = WT [N=1024][K] bf16.
// 128x128 tile, BK=64, 4 waves (2x2), 16x16x32 bf16 MFMA.
// q is folded into the accumulator init (MFMA C-in), no q LDS stage.
// Writes partial logits pl[nblk][b][l]  (transposed for coalesced softmax).
__global__ __launch_bounds__(256, 4) void k_logits(const float* __restrict__ enc,
                                                   const unsigned short* __restrict__ WT,
                                                   const float* __restrict__ qv,
                                                   const float* __restrict__ v,
                                                   float* __restrict__ pl) {
  __shared__ __align__(16) unsigned short As[128 * 64];
  __shared__ __align__(16) unsigned short Bs[128 * 64];
  __shared__ float red[2][128];

  const int tid = threadIdx.x;
  // XCD-aware mapping: all 8 n-blocks of an m-panel land on one XCD (wid%8 heuristic)
  const int xcd = blockIdx.x & 7, slot = blockIdx.x >> 3;
  const int nblk = slot & 7;
  const int mblk = xcd + ((slot >> 3) << 3);
  const int row0 = mblk << 7;
  const int n0 = nblk << 7;

  const int w = tid >> 6, lane = tid & 63;
  const int wr = w >> 1, wc = w & 1;
  const int g = lane >> 4, rr = lane & 15;

  float vreg[4];
#pragma unroll
  for (int nf = 0; nf < 4; ++nf) vreg[nf] = v[n0 + wc * 64 + nf * 16 + rr];

  // seed accumulator with q[b][col]: C/D row = wr*64+mf*16+g*4+rg, b = row&31
  f32x4 acc[4][4];
#pragma unroll
  for (int mf = 0; mf < 4; ++mf)
#pragma unroll
    for (int nf = 0; nf < 4; ++nf)
#pragma unroll
      for (int rg = 0; rg < 4; ++rg) {
        int b = ((mf & 1) << 4) + (g << 2) + rg;
        acc[mf][nf][rg] = qv[((size_t)b << 10) + n0 + wc * 64 + nf * 16 + rr];
      }

  const int ar = tid >> 4;    // A-staging base row (row = ar + 16*i, row&7 == ar&7)
  const int ac4 = tid & 15;   // float4 index within row
  const int ablk = ((ac4 >> 1) ^ (ar & 7));  // swizzled 16B block
  const int brow = lane >> 3, bjj = lane & 7;

  for (int kt = 0; kt < 16; ++kt) {
    const int k0 = kt << 6;
    __syncthreads();
    // --- B tile: global_load_lds, LDS linear, source pre-swizzled ---
#pragma unroll
    for (int c = 0; c < 4; ++c) {
      int nrow = w * 32 + c * 8 + brow;
      int blk = bjj ^ (brow & 7);
      const char* src = (const char*)WT + (((size_t)(n0 + nrow) << 10) + k0) * 2 + (blk << 4);
      load_lds16(src, (void*)&Bs[(w * 32 + c * 8) * 64]);
    }
    // --- A tile: fp32 load -> cvt_pk bf16 -> swizzled ds_write_b64 ---
#pragma unroll
    for (int i = 0; i < 8; ++i) {
      int r = ar + (i << 4);
      f32x4 a4 = *reinterpret_cast<const f32x4*>(enc + (((size_t)(row0 + r)) << 10) + k0 + (ac4 << 2));
      bf16x4 pk = {(__bf16)a4.x, (__bf16)a4.y, (__bf16)a4.z, (__bf16)a4.w};
      *reinterpret_cast<bf16x4*>(&As[r * 64 + (ablk << 3) + ((ac4 & 1) << 2)]) = pk;
    }
    __syncthreads();
    // --- compute: 2 k-steps x 16 frags ---
#pragma unroll
    for (int kk = 0; kk < 2; ++kk) {
      short8 af[4], bfr[4];
#pragma unroll
      for (int mf = 0; mf < 4; ++mf) {
        int r = wr * 64 + mf * 16 + rr;
        int blk = (kk * 4 + g) ^ (r & 7);
        af[mf] = *reinterpret_cast<const short8*>(&As[r * 64 + (blk << 3)]);
      }
#pragma unroll
      for (int nf = 0; nf < 4; ++nf) {
        int r = wc * 64 + nf * 16 + rr;
        int blk = (kk * 4 + g) ^ (r & 7);
        bfr[nf] = *reinterpret_cast<const short8*>(&Bs[r * 64 + (blk << 3)]);
      }
#pragma unroll
      for (int mf = 0; mf < 4; ++mf)
#pragma unroll
        for (int nf = 0; nf < 4; ++nf)
          acc[mf][nf] = __builtin_amdgcn_mfma_f32_16x16x32_bf16(af[mf], bfr[nf], acc[mf][nf], 0, 0, 0);
    }
  }

  // --- epilogue: tanh(S+q)*v, reduce over this block's 128 n-columns ---
#pragma unroll
  for (int mf = 0; mf < 4; ++mf) {
#pragma unroll
    for (int rg = 0; rg < 4; ++rg) {
      int lrow = wr * 64 + mf * 16 + g * 4 + rg;   // C/D: col=lane&15, row=4*(lane>>4)+reg
      float s = 0.f;
#pragma unroll
      for (int nf = 0; nf < 4; ++nf) {
        s += fast_tanh(acc[mf][nf][rg]) * vreg[nf];
      }
      s += __shfl_xor(s, 1);
      s += __shfl_xor(s, 2);
      s += __shfl_xor(s, 4);
      s += __shfl_xor(s, 8);
      if (rr == 0) red[wc][lrow] = s;
    }
  }
  __syncthreads();
  if (tid < 128) {
    int row = row0 + tid;                          // row = l*32 + b
    pl[((size_t)nblk << 16) + ((size_t)(row & 31) << 11) + (row >> 5)] =
        red[0][tid] + red[1][tid];
  }
}

// ---------------- softmax over l, per b ------------------------------------------
__global__ __launch_bounds__(256) void k_softmax(const float* __restrict__ pl,
                                                 const float* __restrict__ mask,
                                                 float* __restrict__ al) {
  const int b = blockIdx.x, t = threadIdx.x;
  __shared__ float sr[256];
  float lg[8];
  float mx = -3.4e38f;
#pragma unroll
  for (int i = 0; i < 8; ++i) {
    int l = t + (i << 8);
    float s = mask[(l << 5) + b];
#pragma unroll
    for (int nb = 0; nb < 8; ++nb) s += pl[((size_t)nb << 16) + (b << 11) + l];
    lg[i] = s;
    mx = fmaxf(mx, s);
  }
  sr[t] = mx;
  __syncthreads();
  for (int off = 128; off > 0; off >>= 1) {
    if (t < off) sr[t] = fmaxf(sr[t], sr[t + off]);
    __syncthreads();
  }
  const float M = sr[0];
  __syncthreads();
  float sum = 0.f;
#pragma unroll
  for (int i = 0; i < 8; ++i) {
    lg[i] = __expf(lg[i] - M);
    sum += lg[i];
  }
  sr[t] = sum;
  __syncthreads();
  for (int off = 128; off > 0; off >>= 1) {
    if (t < off) sr[t] += sr[t + off];
    __syncthreads();
  }
  const float inv = 1.f / sr[0];
#pragma unroll
  for (int i = 0; i < 8; ++i) {
    int l = t + (i << 8);
    al[(l << 5) + b] = lg[i] * inv;
  }
}

// ---------------- context partials: grid = 32 chunks x 32 b ----------------------
__global__ __launch_bounds__(256) void k_ctx(const float* __restrict__ enc,
                                             const float* __restrict__ al,
                                             float* __restrict__ pctx) {
  const int b = blockIdx.x & 31, ch = blockIdx.x >> 5;
  const int t = threadIdx.x;
  __shared__ float wl[64];
  if (t < 64) wl[t] = al[(((ch << 6) + t) << 5) + b];
  __syncthreads();
  f32x4 acc = (f32x4){0.f, 0.f, 0.f, 0.f};
  const float* base = enc + (((size_t)ch * 2048 + b) << 10) + (t << 2);
#pragma unroll 8
  for (int i = 0; i < 64; ++i) {
    f32x4 e = *reinterpret_cast<const f32x4*>(base + (size_t)i * 32768);
    acc += wl[i] * e;
  }
  *reinterpret_cast<f32x4*>(((float*)pctx) + ((size_t)blockIdx.x << 10) + (t << 2)) = acc;
}

__global__ __launch_bounds__(256) void k_ctxred(const float* __restrict__ pctx,
                                                float* __restrict__ out) {
  int i = blockIdx.x * 256 + threadIdx.x;  // 32768 = b*1024 + e
  int b = i >> 10, e = i & 1023;
  float s = 0.f;
#pragma unroll
  for (int ch = 0; ch < 32; ++ch) s += pctx[(size_t)((ch << 5) + b) * 1024 + e];
  out[i] = s;
}

extern "C" void kernel_launch(void* const* d_in, const int* in_sizes, int n_in,
                              void* d_out, int out_size, void* d_ws, size_t ws_size,
                              hipStream_t stream) {
  const float* enc = (const float*)d_in[0];
  const float* mask = (const float*)d_in[1];
  const float* hidden = (const float*)d_in[2];
  const float* Wenc = (const float*)d_in[3];
  const float* battn = (const float*)d_in[4];
  const float* Whid = (const float*)d_in[5];
  const float* v = (const float*)d_in[6];
  float* out = (float*)d_out;          // [0,32768) context [B][ENC]; [32768,98304) alignment [L][B]
  char* ws = (char*)d_ws;

  unsigned short* WT = (unsigned short*)ws;                       // 2 MB
  float* q = (float*)(ws + (2u << 20));                           // 128 KB
  float* pq = (float*)(ws + (2u << 20) + (128u << 10));           // 1 MB
  float* pl = (float*)(ws + (3u << 20) + (128u << 10));           // 2 MB
  float* pctx = (float*)(ws + (5u << 20) + (128u << 10));         // 4 MB
  float* align_out = out + 32768;

  k_wt<<<256, 256, 0, stream>>>(Wenc, WT);
  k_qpart<<<64, 128, 0, stream>>>(hidden, Whid, pq);
  k_qred<<<128, 256, 0, stream>>>(pq, battn, q);
  k_logits<<<4096, 256, 0, stream>>>(enc, WT, q, v, pl);
  k_softmax<<<32, 256, 0, stream>>>(pl, mask, align_out);
  k_ctx<<<1024, 256, 0, stream>>>(enc, align_out, pctx);
  k_ctxred<<<128, 256, 0, stream>>>(pctx, out);
}

// Round 3
// 319.377 us; speedup vs baseline: 1.3813x; 1.3813x over previous
//
#include <hip/hip_runtime.h>
#include <stdint.h>

#define L_DIM 2048
#define B_DIM 32
#define ENC_DIM 1024
#define M_DIM (L_DIM * B_DIM)

typedef __attribute__((ext_vector_type(4))) float f32x4;
typedef __attribute__((ext_vector_type(8))) short short8;
typedef __attribute__((ext_vector_type(4))) __bf16 bf16x4;

static __device__ __forceinline__ float fast_tanh(float x) {
  float cx = fminf(fmaxf(x, -15.f), 15.f);
  float e = __expf(2.f * cx);
  return (e - 1.f) * __frcp_rn(e + 1.f);
}

static __device__ __forceinline__ void load_lds16(const void* g, void* l) {
  __builtin_amdgcn_global_load_lds((const __attribute__((address_space(1))) void*)g,
                                   (__attribute__((address_space(3))) void*)l, 16, 0, 0);
}

// ---------------- W_enc [K=1024][N=1024] fp32  ->  WT [N][K] bf16 -----------------
__global__ __launch_bounds__(256) void k_wt(const float* __restrict__ W,
                                            unsigned short* __restrict__ WT) {
  __shared__ float tile[64][65];
  const int t = threadIdx.x;
  const int k0 = (blockIdx.x & 15) << 6, n0 = (blockIdx.x >> 4) << 6;
#pragma unroll
  for (int i = 0; i < 16; ++i) {
    int idx = t + (i << 8);
    tile[idx >> 6][idx & 63] = W[(size_t)(k0 + (idx >> 6)) * 1024 + n0 + (idx & 63)];
  }
  __syncthreads();
#pragma unroll
  for (int i = 0; i < 16; ++i) {
    int idx = t + (i << 8);
    int r = idx >> 6, c = idx & 63;
    WT[(size_t)(n0 + r) * 1024 + k0 + c] =
        __builtin_bit_cast(unsigned short, (__bf16)tile[c][r]);
  }
}

// ---------------- q partial: grid 64 = 8 a-blocks x 8 h-blocks, 128 thr -----------
__global__ __launch_bounds__(128) void k_qpart(const float* __restrict__ hidden,
                                               const float* __restrict__ Wh,
                                               float* __restrict__ pq) {
  const int ablk = blockIdx.x & 7, hblk = blockIdx.x >> 3;
  const int a = (ablk << 7) + threadIdx.x;
  float acc[32];
#pragma unroll
  for (int b = 0; b < 32; ++b) acc[b] = 0.f;
  const int h0 = hblk << 7;
  for (int h = h0; h < h0 + 128; ++h) {
    float wv = Wh[(size_t)h * 1024 + a];
#pragma unroll
    for (int b = 0; b < 32; ++b) acc[b] = fmaf(hidden[(b << 10) + h], wv, acc[b]);
  }
#pragma unroll
  for (int b = 0; b < 32; ++b) pq[((size_t)hblk << 15) + (b << 10) + a] = acc[b];
}

__global__ __launch_bounds__(256) void k_qred(const float* __restrict__ pq,
                                              const float* __restrict__ ba,
                                              float* __restrict__ q) {
  int i = blockIdx.x * 256 + threadIdx.x;  // 32768
  float s = ba[i & 1023];
#pragma unroll
  for (int j = 0; j < 8; ++j) s += pq[((size_t)j << 15) + i];
  q[i] = s;
}

// ---------------- fused keys-GEMM + tanh.v reduction ------------------------------
// A = enc viewed [M=65536][K=1024] fp32 (row = l*32+b), B = WT [N=1024][K] bf16.
// 128x128 tile, BK=64, 4 waves (2x2), 16x16x32 bf16 MFMA.
// q is folded into the accumulator init (MFMA C-in), no q LDS stage.
// __launch_bounds__(256,3): 170 unified regs/wave — 4-waves/EU spilled (R2: +24MB scratch)
// Writes partial logits pl[nblk][b][l]  (transposed for coalesced softmax).
__global__ __launch_bounds__(256, 3) void k_logits(const float* __restrict__ enc,
                                                   const unsigned short* __restrict__ WT,
                                                   const float* __restrict__ qv,
                                                   const float* __restrict__ v,
                                                   float* __restrict__ pl) {
  __shared__ __align__(16) unsigned short As[128 * 64];
  __shared__ __align__(16) unsigned short Bs[128 * 64];
  __shared__ float red[2][128];

  const int tid = threadIdx.x;
  // XCD-aware mapping: all 8 n-blocks of an m-panel land on one XCD (wid%8 heuristic)
  const int xcd = blockIdx.x & 7, slot = blockIdx.x >> 3;
  const int nblk = slot & 7;
  const int mblk = xcd + ((slot >> 3) << 3);
  const int row0 = mblk << 7;
  const int n0 = nblk << 7;

  const int w = tid >> 6, lane = tid & 63;
  const int wr = w >> 1, wc = w & 1;
  const int g = lane >> 4, rr = lane & 15;

  float vreg[4];
#pragma unroll
  for (int nf = 0; nf < 4; ++nf) vreg[nf] = v[n0 + wc * 64 + nf * 16 + rr];

  // seed accumulator with q[b][col]: C/D row = wr*64+mf*16+g*4+rg, b = row&31
  f32x4 acc[4][4];
#pragma unroll
  for (int mf = 0; mf < 4; ++mf)
#pragma unroll
    for (int nf = 0; nf < 4; ++nf)
#pragma unroll
      for (int rg = 0; rg < 4; ++rg) {
        int b = ((mf & 1) << 4) + (g << 2) + rg;
        acc[mf][nf][rg] = qv[((size_t)b << 10) + n0 + wc * 64 + nf * 16 + rr];
      }

  const int ar = tid >> 4;    // A-staging base row (row = ar + 16*i, row&7 == ar&7)
  const int ac4 = tid & 15;   // float4 index within row
  const int ablk = ((ac4 >> 1) ^ (ar & 7));  // swizzled 16B block
  const int brow = lane >> 3, bjj = lane & 7;

  for (int kt = 0; kt < 16; ++kt) {
    const int k0 = kt << 6;
    __syncthreads();
    // --- B tile: global_load_lds, LDS linear, source pre-swizzled ---
#pragma unroll
    for (int c = 0; c < 4; ++c) {
      int nrow = w * 32 + c * 8 + brow;
      int blk = bjj ^ (brow & 7);
      const char* src = (const char*)WT + (((size_t)(n0 + nrow) << 10) + k0) * 2 + (blk << 4);
      load_lds16(src, (void*)&Bs[(w * 32 + c * 8) * 64]);
    }
    // --- A tile: fp32 load -> cvt_pk bf16 -> swizzled ds_write_b64 ---
#pragma unroll
    for (int i = 0; i < 8; ++i) {
      int r = ar + (i << 4);
      f32x4 a4 = *reinterpret_cast<const f32x4*>(enc + (((size_t)(row0 + r)) << 10) + k0 + (ac4 << 2));
      bf16x4 pk = {(__bf16)a4.x, (__bf16)a4.y, (__bf16)a4.z, (__bf16)a4.w};
      *reinterpret_cast<bf16x4*>(&As[r * 64 + (ablk << 3) + ((ac4 & 1) << 2)]) = pk;
    }
    __syncthreads();
    // --- compute: 2 k-steps x 16 frags ---
#pragma unroll
    for (int kk = 0; kk < 2; ++kk) {
      short8 af[4], bfr[4];
#pragma unroll
      for (int mf = 0; mf < 4; ++mf) {
        int r = wr * 64 + mf * 16 + rr;
        int blk = (kk * 4 + g) ^ (r & 7);
        af[mf] = *reinterpret_cast<const short8*>(&As[r * 64 + (blk << 3)]);
      }
#pragma unroll
      for (int nf = 0; nf < 4; ++nf) {
        int r = wc * 64 + nf * 16 + rr;
        int blk = (kk * 4 + g) ^ (r & 7);
        bfr[nf] = *reinterpret_cast<const short8*>(&Bs[r * 64 + (blk << 3)]);
      }
#pragma unroll
      for (int mf = 0; mf < 4; ++mf)
#pragma unroll
        for (int nf = 0; nf < 4; ++nf)
          acc[mf][nf] = __builtin_amdgcn_mfma_f32_16x16x32_bf16(af[mf], bfr[nf], acc[mf][nf], 0, 0, 0);
    }
  }

  // --- epilogue: tanh(S+q)*v, reduce over this block's 128 n-columns ---
#pragma unroll
  for (int mf = 0; mf < 4; ++mf) {
#pragma unroll
    for (int rg = 0; rg < 4; ++rg) {
      int lrow = wr * 64 + mf * 16 + g * 4 + rg;   // C/D: col=lane&15, row=4*(lane>>4)+reg
      float s = 0.f;
#pragma unroll
      for (int nf = 0; nf < 4; ++nf) {
        s += fast_tanh(acc[mf][nf][rg]) * vreg[nf];
      }
      s += __shfl_xor(s, 1);
      s += __shfl_xor(s, 2);
      s += __shfl_xor(s, 4);
      s += __shfl_xor(s, 8);
      if (rr == 0) red[wc][lrow] = s;
    }
  }
  __syncthreads();
  if (tid < 128) {
    int row = row0 + tid;                          // row = l*32 + b
    pl[((size_t)nblk << 16) + ((size_t)(row & 31) << 11) + (row >> 5)] =
        red[0][tid] + red[1][tid];
  }
}

// ---------------- softmax over l, per b ------------------------------------------
__global__ __launch_bounds__(256) void k_softmax(const float* __restrict__ pl,
                                                 const float* __restrict__ mask,
                                                 float* __restrict__ al) {
  const int b = blockIdx.x, t = threadIdx.x;
  __shared__ float sr[256];
  float lg[8];
  float mx = -3.4e38f;
#pragma unroll
  for (int i = 0; i < 8; ++i) {
    int l = t + (i << 8);
    float s = mask[(l << 5) + b];
#pragma unroll
    for (int nb = 0; nb < 8; ++nb) s += pl[((size_t)nb << 16) + (b << 11) + l];
    lg[i] = s;
    mx = fmaxf(mx, s);
  }
  sr[t] = mx;
  __syncthreads();
  for (int off = 128; off > 0; off >>= 1) {
    if (t < off) sr[t] = fmaxf(sr[t], sr[t + off]);
    __syncthreads();
  }
  const float M = sr[0];
  __syncthreads();
  float sum = 0.f;
#pragma unroll
  for (int i = 0; i < 8; ++i) {
    lg[i] = __expf(lg[i] - M);
    sum += lg[i];
  }
  sr[t] = sum;
  __syncthreads();
  for (int off = 128; off > 0; off >>= 1) {
    if (t < off) sr[t] += sr[t + off];
    __syncthreads();
  }
  const float inv = 1.f / sr[0];
#pragma unroll
  for (int i = 0; i < 8; ++i) {
    int l = t + (i << 8);
    al[(l << 5) + b] = lg[i] * inv;
  }
}

// ---------------- context partials: grid = 32 chunks x 32 b ----------------------
__global__ __launch_bounds__(256) void k_ctx(const float* __restrict__ enc,
                                             const float* __restrict__ al,
                                             float* __restrict__ pctx) {
  const int b = blockIdx.x & 31, ch = blockIdx.x >> 5;
  const int t = threadIdx.x;
  __shared__ float wl[64];
  if (t < 64) wl[t] = al[(((ch << 6) + t) << 5) + b];
  __syncthreads();
  f32x4 acc = (f32x4){0.f, 0.f, 0.f, 0.f};
  const float* base = enc + (((size_t)ch * 2048 + b) << 10) + (t << 2);
#pragma unroll 8
  for (int i = 0; i < 64; ++i) {
    f32x4 e = *reinterpret_cast<const f32x4*>(base + (size_t)i * 32768);
    acc += wl[i] * e;
  }
  *reinterpret_cast<f32x4*>(((float*)pctx) + ((size_t)blockIdx.x << 10) + (t << 2)) = acc;
}

__global__ __launch_bounds__(256) void k_ctxred(const float* __restrict__ pctx,
                                                float* __restrict__ out) {
  int i = blockIdx.x * 256 + threadIdx.x;  // 32768 = b*1024 + e
  int b = i >> 10, e = i & 1023;
  float s = 0.f;
#pragma unroll
  for (int ch = 0; ch < 32; ++ch) s += pctx[(size_t)((ch << 5) + b) * 1024 + e];
  out[i] = s;
}

extern "C" void kernel_launch(void* const* d_in, const int* in_sizes, int n_in,
                              void* d_out, int out_size, void* d_ws, size_t ws_size,
                              hipStream_t stream) {
  const float* enc = (const float*)d_in[0];
  const float* mask = (const float*)d_in[1];
  const float* hidden = (const float*)d_in[2];
  const float* Wenc = (const float*)d_in[3];
  const float* battn = (const float*)d_in[4];
  const float* Whid = (const float*)d_in[5];
  const float* v = (const float*)d_in[6];
  float* out = (float*)d_out;          // [0,32768) context [B][ENC]; [32768,98304) alignment [L][B]
  char* ws = (char*)d_ws;

  unsigned short* WT = (unsigned short*)ws;                       // 2 MB
  float* q = (float*)(ws + (2u << 20));                           // 128 KB
  float* pq = (float*)(ws + (2u << 20) + (128u << 10));           // 1 MB
  float* pl = (float*)(ws + (3u << 20) + (128u << 10));           // 2 MB
  float* pctx = (float*)(ws + (5u << 20) + (128u << 10));         // 4 MB
  float* align_out = out + 32768;

  k_wt<<<256, 256, 0, stream>>>(Wenc, WT);
  k_qpart<<<64, 128, 0, stream>>>(hidden, Whid, pq);
  k_qred<<<128, 256, 0, stream>>>(pq, battn, q);
  k_logits<<<4096, 256, 0, stream>>>(enc, WT, q, v, pl);
  k_softmax<<<32, 256, 0, stream>>>(pl, mask, align_out);
  k_ctx<<<1024, 256, 0, stream>>>(enc, align_out, pctx);
  k_ctxred<<<128, 256, 0, stream>>>(pctx, out);
}